// Round 1
// baseline (306.050 us; speedup 1.0000x reference)
//
#include <hip/hip_runtime.h>
#include <math.h>

#define NB 32
#define DIM 256
#define SCALE_QK 0.35355339059327373f

typedef float floatx4 __attribute__((ext_vector_type(4)));   // native vec for nontemporal

// ---------------------------------------------------------------------------
// K1: per-(b,c) plane row/col means.  x:(B,256,64,64) -> xh[b][c][h], xw[b][c][w]
// v2: no LDS staging of the plane. Row sums reduce in-register via 16-lane
// shfl butterfly at load time; column partials accumulate per-thread (same
// 4-column slot across the i-loop), reduce across the wave (xor 16/32), and
// a 1.25 KB LDS buffer combines the 4 per-wave partials.
// Also zeroes the 32 per-batch arrival counters used by K2's fused gate.
// ---------------------------------------------------------------------------
__global__ __launch_bounds__(256) void k_reduce(const float* __restrict__ x,
                                                float* __restrict__ xh,
                                                float* __restrict__ xw,
                                                int* __restrict__ cnt) {
    __shared__ float srow[64];
    __shared__ float scol[4 * 64];
    const int t = threadIdx.x;
    if (blockIdx.x == 0 && t < 32) cnt[t] = 0;   // stream-ordered before K2
    const float* p = x + (size_t)blockIdx.x * 4096;
    float4 colp = {0.f, 0.f, 0.f, 0.f};
#pragma unroll
    for (int i = 0; i < 4; ++i) {
        int idx4 = t + 256 * i;                  // float4 index in plane
        float4 v = reinterpret_cast<const float4*>(p)[idx4];
        colp.x += v.x; colp.y += v.y; colp.z += v.z; colp.w += v.w;
        // row partial: 16 consecutive lanes share row h = (t>>4) + 16*i
        float r = v.x + v.y + v.z + v.w;
#pragma unroll
        for (int off = 1; off <= 8; off <<= 1) r += __shfl_xor(r, off, 64);
        if ((t & 15) == 0) srow[(t >> 4) + 16 * i] = r * (1.0f / 64.0f);
    }
    // column partials: lanes sharing (t&15) within a wave cover 16 distinct rows
#pragma unroll
    for (int off = 16; off <= 32; off <<= 1) {
        colp.x += __shfl_xor(colp.x, off, 64);
        colp.y += __shfl_xor(colp.y, off, 64);
        colp.z += __shfl_xor(colp.z, off, 64);
        colp.w += __shfl_xor(colp.w, off, 64);
    }
    const int wv = t >> 6, ln = t & 63;
    if (ln < 16) *reinterpret_cast<float4*>(&scol[wv * 64 + ln * 4]) = colp;
    __syncthreads();
    if (t < 64) {
        xh[(size_t)blockIdx.x * 64 + t] = srow[t];
        xw[(size_t)blockIdx.x * 64 + t] =
            (scol[t] + scol[64 + t] + scol[128 + t] + scol[192 + t]) * (1.0f / 64.0f);
    }
}

// ---------------------------------------------------------------------------
// K2: per (b, axis, head): qkv = BN(w_qkv @ x_axis); q,k += pos; attention.
// Emits outa[(b,axis,c),l] + outam mean slice; the LAST block of each batch
// (device-scope atomic arrival) runs the SE gate MLP inline -> g2out.
// grid = 128 blocks (b*4 + axis*2 + head), 256 threads.
// v2: softmax wave-parallel (4 lanes/row, contiguous 16-col chunks,
// conflict-free, quad shfl reduce) instead of 64-thread serial loops.
// ---------------------------------------------------------------------------
__global__ __launch_bounds__(256) void k_qkv_attn(
    const float* __restrict__ xh, const float* __restrict__ xw,
    const float* __restrict__ w_qkv, const float* __restrict__ qscale,
    const float* __restrict__ qshift, const float* __restrict__ pos_h,
    const float* __restrict__ pos_w, float* __restrict__ outa,
    float* __restrict__ outam, int* __restrict__ cnt,
    const float* __restrict__ w_fusion, const float* __restrict__ fscale,
    const float* __restrict__ fshift, const float* __restrict__ w_g1,
    const float* __restrict__ g1s, const float* __restrict__ g1b,
    const float* __restrict__ w_g2, const float* __restrict__ g2s,
    const float* __restrict__ g2b, float* __restrict__ g2out) {
    const int blk = blockIdx.x;
    const int head = blk & 1;
    const int axis = (blk >> 1) & 1;
    const int b = blk >> 2;
    const float* xa = (axis ? xw : xh) + (size_t)b * DIM * 64;
    const float* pos = axis ? pos_w : pos_h;

    __shared__ float smem[16384];          // 64 KB, phase-unioned
    __shared__ int sIsLast;
    float* sx = smem;                      // phase 1: x_axis [c][l], 256*64
    float* sq = smem;                      // phase 2: qkv rows [24][64] (q0-7,k8-15,v16-23)
    float* sP = smem + 24 * 64;            // phase 2: logits [64][65]

    const int t = threadIdx.x;
#pragma unroll
    for (int i = 0; i < 16; ++i) {
        int idx4 = t + 256 * i;
        reinterpret_cast<float4*>(sx)[idx4] =
            reinterpret_cast<const float4*>(xa)[idx4];
    }
    __syncthreads();

    const int l = t & 63, g = t >> 6;
    float acc[6] = {0.f, 0.f, 0.f, 0.f, 0.f, 0.f};
    int ocg[6];
#pragma unroll
    for (int i = 0; i < 6; ++i) {
        int r = g + 4 * i;                       // row 0..23
        ocg[i] = (r >> 3) * 16 + head * 8 + (r & 7);   // global qkv channel
    }
    for (int c = 0; c < 256; c += 4) {
        float x0 = sx[(c + 0) * 64 + l];
        float x1 = sx[(c + 1) * 64 + l];
        float x2 = sx[(c + 2) * 64 + l];
        float x3 = sx[(c + 3) * 64 + l];
#pragma unroll
        for (int i = 0; i < 6; ++i) {
            float4 wv = *reinterpret_cast<const float4*>(&w_qkv[ocg[i] * 256 + c]);
            acc[i] += wv.x * x0 + wv.y * x1 + wv.z * x2 + wv.w * x3;
        }
    }
    __syncthreads();                           // done reading sx; smem reused
    float vals[6];
#pragma unroll
    for (int i = 0; i < 6; ++i) {
        int r = g + 4 * i;
        float v = acc[i] * qscale[ocg[i]] + qshift[ocg[i]];
        if (r < 16) v += pos[(head * 8 + (r & 7)) * 64 + l];   // q and k get pos
        vals[i] = v;
    }
#pragma unroll
    for (int i = 0; i < 6; ++i) sq[(g + 4 * i) * 64 + l] = vals[i];
    __syncthreads();

    // logits S[i][j] = SCALE * sum_d q[d][i] k[d][j]
    {
        const int j = t & 63;
#pragma unroll
        for (int ii = 0; ii < 16; ++ii) {
            int i = g + 4 * ii;
            float s = 0.f;
#pragma unroll
            for (int d = 0; d < 8; ++d)
                s += sq[d * 64 + i] * sq[(8 + d) * 64 + j];
            sP[i * 65 + j] = s * SCALE_QK;
        }
    }
    __syncthreads();
    // softmax per row: 4 lanes per row, contiguous 16-col chunk each.
    // addr = 65r + 16q + j -> bank (r + 16q + j) % 32 : exact 2-way, free.
    {
        const int r = t >> 2, q = t & 3;
        float* row = &sP[r * 65 + q * 16];
        float m = -1e30f;
#pragma unroll
        for (int j = 0; j < 16; ++j) m = fmaxf(m, row[j]);
        m = fmaxf(m, __shfl_xor(m, 1, 64));
        m = fmaxf(m, __shfl_xor(m, 2, 64));
        float sum = 0.f;
#pragma unroll
        for (int j = 0; j < 16; ++j) {
            float e = __expf(row[j] - m);
            row[j] = e;
            sum += e;
        }
        sum += __shfl_xor(sum, 1, 64);
        sum += __shfl_xor(sum, 2, 64);
        float rinv = 1.0f / sum;
#pragma unroll
        for (int j = 0; j < 16; ++j) row[j] *= rinv;
    }
    __syncthreads();
    // out[d][i] = sum_j P[i][j] v[d][j]; also emit mean over i
    {
        const int i = t & 63;
#pragma unroll
        for (int k2 = 0; k2 < 2; ++k2) {
            int d = g * 2 + k2;
            float acc2 = 0.f;
            for (int j = 0; j < 64; ++j)
                acc2 += sP[i * 65 + j] * sq[(16 + d) * 64 + j];
            outa[(((size_t)b * 2 + axis) * 16 + head * 8 + d) * 64 + i] = acc2;
            float s = acc2;                     // wave butterfly over the 64 lanes
#pragma unroll
            for (int off = 32; off >= 1; off >>= 1) s += __shfl_xor(s, off, 64);
            if (i == 0)
                outam[((size_t)b * 2 + axis) * 16 + head * 8 + d] = s * (1.0f / 64.0f);
        }
    }

    // ---- last block of this batch runs the SE gate inline -------------------
    __threadfence();                           // release outam writes (device scope)
    if (t == 0) sIsLast = (atomicAdd(&cnt[b], 1) == 3) ? 1 : 0;
    __syncthreads();
    if (sIsLast) {
        float* sm  = smem;                     // 32
        float* sg  = smem + 64;                // 256
        float* sg1 = smem + 64 + 256;          // 64
        if (t < 32)
            sm[t] = __hip_atomic_load(&outam[(size_t)b * 32 + t],
                                      __ATOMIC_ACQUIRE, __HIP_MEMORY_SCOPE_AGENT);
        __syncthreads();
        {
            float a2 = 0.f;
#pragma unroll
            for (int c = 0; c < 32; c += 4) {
                float4 wv = *reinterpret_cast<const float4*>(&w_fusion[t * 32 + c]);
                a2 += wv.x * sm[c] + wv.y * sm[c + 1] + wv.z * sm[c + 2] + wv.w * sm[c + 3];
            }
            sg[t] = a2 * fscale[t] + fshift[t];
        }
        __syncthreads();
        if (t < 64) {
            float a2 = 0.f;
            for (int c = 0; c < 256; c += 4) {
                float4 wv = *reinterpret_cast<const float4*>(&w_g1[t * 256 + c]);
                a2 += wv.x * sg[c] + wv.y * sg[c + 1] + wv.z * sg[c + 2] + wv.w * sg[c + 3];
            }
            float v = a2 * g1s[t] + g1b[t];
            sg1[t] = v / (1.0f + __expf(-v));            // silu
        }
        __syncthreads();
        {
            float a2 = 0.f;
#pragma unroll
            for (int j = 0; j < 64; j += 4) {
                float4 wv = *reinterpret_cast<const float4*>(&w_g2[t * 64 + j]);
                a2 += wv.x * sg1[j] + wv.y * sg1[j + 1] + wv.z * sg1[j + 2] + wv.w * sg1[j + 3];
            }
            float v = a2 * g2s[t] + g2b[t];
            g2out[(size_t)b * 256 + t] = 0.1f / (1.0f + __expf(-v));   // 0.1*sigmoid folded
        }
    }
}

// ---------------------------------------------------------------------------
// K3: fusion row recompute + epilogue.
// out = x + gv*(fscale*(rowh[h]+roww[w]) + fshift).  grid = 8192 (b*256+o).
// ---------------------------------------------------------------------------
__global__ __launch_bounds__(256) void k_final(
    const float* __restrict__ x, const float* __restrict__ outa,
    const float* __restrict__ w_fusion, const float* __restrict__ fscale,
    const float* __restrict__ fshift, const float* __restrict__ g2,
    float* __restrict__ out) {
    const int bo = blockIdx.x;
    const int b = bo >> 8, o = bo & 255;
    __shared__ float so[2048];             // outa[b] : [axis][c][l]
    __shared__ float sP[64], sQ[64];
    const int t = threadIdx.x;
    const float* oa = outa + (size_t)b * 2048;
    reinterpret_cast<float4*>(so)[t] = reinterpret_cast<const float4*>(oa)[t];
    reinterpret_cast<float4*>(so)[t + 256] = reinterpret_cast<const float4*>(oa)[t + 256];
    const float gv = g2[bo];               // already 0.1*sigmoid
    __syncthreads();
    if (t < 64) {                          // rowh over axis 0 (block-uniform weights)
        float acc = 0.f;
#pragma unroll
        for (int c = 0; c < 16; ++c) acc += w_fusion[o * 32 + c] * so[c * 64 + t];
        sP[t] = gv * (fscale[o] * acc + fshift[o]);
    } else if (t < 128) {                  // roww over axis 1
        int w = t - 64;
        float acc = 0.f;
#pragma unroll
        for (int c = 0; c < 16; ++c)
            acc += w_fusion[o * 32 + 16 + c] * so[1024 + c * 64 + w];
        sQ[w] = gv * fscale[o] * acc;
    }
    __syncthreads();
    const float* px = x + (size_t)bo * 4096;
    float* po = out + (size_t)bo * 4096;
#pragma unroll
    for (int i = 0; i < 4; ++i) {
        int idx4 = t + 256 * i;
        float4 xv = reinterpret_cast<const float4*>(px)[idx4];
        int h = idx4 >> 4, w0 = (idx4 & 15) << 2;
        float a = sP[h];
        floatx4 r;
        r.x = xv.x + a + sQ[w0 + 0];
        r.y = xv.y + a + sQ[w0 + 1];
        r.z = xv.z + a + sQ[w0 + 2];
        r.w = xv.w + a + sQ[w0 + 3];
        __builtin_nontemporal_store(r, reinterpret_cast<floatx4*>(po) + idx4);
    }
}

extern "C" void kernel_launch(void* const* d_in, const int* in_sizes, int n_in,
                              void* d_out, int out_size, void* d_ws, size_t ws_size,
                              hipStream_t stream) {
    const float* x      = (const float*)d_in[0];
    const float* w_qkv  = (const float*)d_in[1];
    const float* qscale = (const float*)d_in[2];
    const float* qshift = (const float*)d_in[3];
    const float* pos_h  = (const float*)d_in[4];
    const float* pos_w  = (const float*)d_in[5];
    const float* w_fus  = (const float*)d_in[6];
    const float* fscale = (const float*)d_in[7];
    const float* fshift = (const float*)d_in[8];
    const float* w_g1   = (const float*)d_in[9];
    const float* g1s    = (const float*)d_in[10];
    const float* g1b    = (const float*)d_in[11];
    const float* w_g2   = (const float*)d_in[12];
    const float* g2s    = (const float*)d_in[13];
    const float* g2b    = (const float*)d_in[14];
    float* out = (float*)d_out;

    // workspace layout (floats)
    float* ws    = (float*)d_ws;
    float* xh    = ws;                    // 32*256*64 = 524288
    float* xw    = xh + 524288;           // 524288
    float* outa  = xw + 524288;           // 32*2*16*64 = 65536
    float* outam = outa + 65536;          // 32*32 = 1024
    float* g2w   = outam + 1024;          // 32*256 = 8192
    int*   cnt   = (int*)(g2w + 8192);    // 32 arrival counters

    k_reduce<<<NB * DIM, 256, 0, stream>>>(x, xh, xw, cnt);
    k_qkv_attn<<<NB * 4, 256, 0, stream>>>(xh, xw, w_qkv, qscale, qshift,
                                           pos_h, pos_w, outa, outam, cnt,
                                           w_fus, fscale, fshift,
                                           w_g1, g1s, g1b, w_g2, g2s, g2b, g2w);
    k_final<<<NB * DIM, 256, 0, stream>>>(x, outa, w_fus, fscale, fshift, g2w, out);
}